// Round 7
// baseline (228.489 us; speedup 1.0000x reference)
//
#include <hip/hip_runtime.h>

// ComplexSKPDELayer — MFMA formulation (R11 = R10 with cvt_pkrtz type fix).
// Ledger: R1 118us c-inner (256,2) inline prep. R6 636us spill ((512,4)).
// R7 150us c-inner GRID=1024 (288 combined regs -> extra blocks can't land).
// R8 190us c-outer (256,3) -> frag-set spill 270MB. R9 128us c-outer (256,2):
// conflicts 0, prep offloaded, VGPR=128+20agpr=148 combined, no big spill —
// but Occupancy 16.5% == EXACTLY 8 waves/CU == GRID-limited (512 blocks =
// 2/CU). 148*3=444<=512 regs and 3*36.9=110<=160 KiB LDS -> 3 blocks/CU fit.
// R10/R11: GRID=1024 (5 tiles/wave, no tail). Plus VALU cut: explicit
// v_cvt_pkrtz f32x2->f16x2 packing of A-frags via shufflevector (SSA, no
// memory). R10 failed to compile: cvt_pkrtz returns __fp16x2, not _Float16x2
// -> bit_cast wrapper. Keep (256,2): R8 proved (256,3) spills this structure.
//
// Math (unchanged): per interior point, Helmholtz residual = 5 matvecs
// through W2: rows h1,g1x,g1y,g1z,s1 -> z2,ux,uy,uz,t; h2=tanh(z2+b2);
// lap_k=d2*(t-2*h2*(ux^2+uy^2+uz^2)); helm=(lap_k+4*h2)@W3(+4*b3).
// C/D layout col=lane&15(=k), row=(lane>>4)*4+reg(=point) -> lane-local
// epilogue + 16-lane shfl reduce. fp16 absmax ~0.008 vs 0.27 threshold.

#define N_INT 262144
#define N_BC  65536
#define HID   128
#define GRID  1024
#define WPB   4                      // waves per 256-thread block
#define NWAVE (GRID * WPB)           // 4096 waves
#define TILES_INT (N_INT / 16)       // 16384
#define TILES_BC  (N_BC / 16)        // 4096
#define TILES_ALL (TILES_INT + TILES_BC)   // 20480 = 4096 * 5, no tail

typedef _Float16 h8 __attribute__((ext_vector_type(8)));
typedef _Float16 h4 __attribute__((ext_vector_type(4)));
typedef _Float16 h2 __attribute__((ext_vector_type(2)));
typedef __fp16   g2 __attribute__((ext_vector_type(2)));   // cvt_pkrtz native
typedef float    f4 __attribute__((ext_vector_type(4)));

__device__ __forceinline__ float ftanh(float x) {
    // tanh(x) = 1 - 2/(e^{2x}+1); v_exp_f32 + v_rcp_f32, ~2 ulp, inf-safe
    float e = __expf(2.0f * x);
    return 1.0f - 2.0f * __builtin_amdgcn_rcpf(e + 1.0f);
}

__device__ __forceinline__ h2 pk(float a, float b) {
    g2 t = __builtin_amdgcn_cvt_pkrtz(a, b);       // one v_cvt_pkrtz_f16_f32
    return __builtin_bit_cast(h2, t);
}

__device__ __forceinline__ h8 pack8(h2 a, h2 b, h2 c, h2 d) {
    h4 lo = __builtin_shufflevector(a, b, 0, 1, 2, 3);
    h4 hi = __builtin_shufflevector(c, d, 0, 1, 2, 3);
    return __builtin_shufflevector(lo, hi, 0, 1, 2, 3, 4, 5, 6, 7);
}

// ---------------- one-time prep: pack W2 + derived consts into ws ----------
// wsB (offset 0):      16384 fp16 = 32 KiB, B-frag order:
//   wsB[(((s*8+c)*64)+(qd*16+nn))*8+i] = fp16 W2[s*32+qd*8+i][c*16+nn]
// wsF (offset 32768):  1024 f32 = 4 KiB:
//   [0:512)   P[j] = float4{Wx,Wy,Wz,C1}[j], C1 = b1 + latent@W1[3:]
//   [512:640) Q2 = -2*(Wx^2+Wy^2+Wz^2)
//   [640:768) b2
//   [768:1024) W3 (128x2 interleaved)
extern "C" __global__ void pde_prep(const float* __restrict__ latent,
                                    const float* __restrict__ W1,
                                    const float* __restrict__ b1,
                                    const float* __restrict__ W2,
                                    const float* __restrict__ b2,
                                    const float* __restrict__ W3,
                                    _Float16* __restrict__ wsB,
                                    float* __restrict__ wsF)
{
    const int tid = threadIdx.x;
    for (int e = 0; e < 64; ++e) {
        int idx = e * 256 + tid;                   // coalesced over W2 row-major
        int j = idx >> 7, n = idx & 127;           // j = K row, n = out col
        int s = j >> 5, qd = (j >> 3) & 3, i = j & 7;
        int c = n >> 4,  nn = n & 15;
        wsB[(((s * 8 + c) * 64) + (qd * 16 + nn)) * 8 + i] = (_Float16)W2[idx];
    }
    // latent reduction: 2 threads per column, 32-deep chains, shfl combine
    {
        int col = tid >> 1, h = tid & 1;
        float acc = 0.0f;
        #pragma unroll
        for (int l = 0; l < 32; ++l)
            acc = fmaf(latent[32 * h + l], W1[(3 + 32 * h + l) * HID + col], acc);
        acc += __shfl_xor(acc, 1);
        if (h == 0) wsF[4 * col + 3] = acc + b1[col];   // P[col].w = C1
    }
    if (tid < HID) {
        float wx = W1[tid], wy = W1[HID + tid], wz = W1[2 * HID + tid];
        wsF[4 * tid]     = wx;                          // P[tid].x
        wsF[4 * tid + 1] = wy;                          // P[tid].y
        wsF[4 * tid + 2] = wz;                          // P[tid].z
        wsF[512 + tid] = -2.0f * fmaf(wx, wx, fmaf(wy, wy, wz * wz));
        wsF[640 + tid] = b2[tid];
        wsF[768 + 2 * tid]     = W3[2 * tid];
        wsF[768 + 2 * tid + 1] = W3[2 * tid + 1];
    }
}

extern "C" __global__ __launch_bounds__(256, 2)
void pde_mfma(const float* __restrict__ ci, const float* __restrict__ cb,
              const float* __restrict__ gt, const float* __restrict__ b3,
              const _Float16* __restrict__ wsB, const float* __restrict__ wsF,
              float* __restrict__ out)
{
    __shared__ float4 sBv[2048];       // 32 KiB packed W2 B-frags
    __shared__ float4 sFv[256];        // 4 KiB derived consts
    _Float16* sB = (_Float16*)sBv;
    const float*  sF  = (const float*)sFv;
    const float4* sP  = (const float4*)sF;          // {wx,wy,wz,c1}[j]
    const float*  sQ2 = sF + 512;
    const float*  sB2 = sF + 640;
    const float2* sW3 = (const float2*)(sF + 768);

    const int tid = threadIdx.x;

    // conflict-free staging copy: 32 KiB + 4 KiB as float4
    #pragma unroll
    for (int e = 0; e < 8; ++e)
        sBv[e * 256 + tid] = ((const float4*)wsB)[e * 256 + tid];
    sFv[tid] = ((const float4*)wsF)[tid];
    __syncthreads();

    const int lane = tid & 63;
    const int m    = lane & 15;        // point-in-tile
    const int qd   = lane >> 4;        // quad: k-subrange / C row block
    const int wgid = blockIdx.x * WPB + (tid >> 6);
    const float b30 = b3[0], b31 = b3[1];
    const f4 z4 = {0.0f, 0.0f, 0.0f, 0.0f};

    float lsum = 0.0f, bsum = 0.0f;

    // coordinate pipeline: coords for tile t preloaded before body
    int t = wgid;
    const float* cp0 = (t < TILES_INT) ? (ci + 3 * (t * 16 + m))
                                       : (cb + 3 * ((t - TILES_INT) * 16 + m));
    float x = cp0[0], y = cp0[1], z = cp0[2];

    for (; t < TILES_ALL; t += NWAVE) {
      // issue next tile's coord loads now; consumed next iteration
      float nx, ny, nz;
      {
        int tn = t + NWAVE;
        if (tn < TILES_ALL) {
            const float* np = (tn < TILES_INT) ? (ci + 3 * (tn * 16 + m))
                                               : (cb + 3 * ((tn - TILES_INT) * 16 + m));
            nx = np[0]; ny = np[1]; nz = np[2];
        } else { nx = ny = nz = 0.0f; }
      }

      if (t < TILES_INT) {
        // ================= interior tile: 16 points =================
        const int p0 = t * 16;

        // A-frags for all 4 k-slices (80 VGPRs live), pkrtz pair-packed
        h8 FH[4], FX[4], FY[4], FZ[4], FT[4];
        #pragma unroll
        for (int s = 0; s < 4; ++s) {
            const int j0 = s * 32 + qd * 8;
            h2 ph[4], px[4], py[4], pz[4], pt2[4];
            #pragma unroll
            for (int i2 = 0; i2 < 4; ++i2) {
                const int jA = j0 + 2 * i2, jB = jA + 1;
                float4 PA = sP[jA], PB = sP[jB];
                float z1A = fmaf(x, PA.x, fmaf(y, PA.y, fmaf(z, PA.z, PA.w)));
                float z1B = fmaf(x, PB.x, fmaf(y, PB.y, fmaf(z, PB.z, PB.w)));
                float hA = ftanh(z1A), hB = ftanh(z1B);
                float dA = fmaf(-hA, hA, 1.0f), dB = fmaf(-hB, hB, 1.0f);
                ph[i2]  = pk(hA, hB);
                px[i2]  = pk(dA * PA.x, dB * PB.x);
                py[i2]  = pk(dA * PA.y, dB * PB.y);
                pz[i2]  = pk(dA * PA.z, dB * PB.z);
                pt2[i2] = pk(sQ2[jA] * hA * dA, sQ2[jB] * hB * dB);
            }
            FH[s] = pack8(ph[0], ph[1], ph[2], ph[3]);
            FX[s] = pack8(px[0], px[1], px[2], px[3]);
            FY[s] = pack8(py[0], py[1], py[2], py[3]);
            FZ[s] = pack8(pz[0], pz[1], pz[2], pz[3]);
            FT[s] = pack8(pt2[0], pt2[1], pt2[2], pt2[3]);
        }

        float yr[4] = {0,0,0,0}, yi[4] = {0,0,0,0};
        float lr[4] = {0,0,0,0}, li[4] = {0,0,0,0};
        #pragma unroll
        for (int c = 0; c < 8; ++c) {
            f4 aZ = z4, aX = z4, aY = z4, aW = z4, aT = z4;
            #pragma unroll
            for (int s = 0; s < 4; ++s) {
                h8 bf = *(const h8*)&sB[(((s * 8 + c) * 64) + lane) * 8];
                aZ = __builtin_amdgcn_mfma_f32_16x16x32_f16(FH[s], bf, aZ, 0, 0, 0);
                aX = __builtin_amdgcn_mfma_f32_16x16x32_f16(FX[s], bf, aX, 0, 0, 0);
                aY = __builtin_amdgcn_mfma_f32_16x16x32_f16(FY[s], bf, aY, 0, 0, 0);
                aW = __builtin_amdgcn_mfma_f32_16x16x32_f16(FZ[s], bf, aW, 0, 0, 0);
                aT = __builtin_amdgcn_mfma_f32_16x16x32_f16(FT[s], bf, aT, 0, 0, 0);
            }
            // fused epilogue for this c: lane-local (point=qd*4+r, k=c*16+m)
            const int k = c * 16 + m;
            const float b2k = sB2[k];
            const float2 w3 = sW3[k];
            #pragma unroll
            for (int r = 0; r < 4; ++r) {
                float h2v = ftanh(aZ[r] + b2k);
                float d2 = fmaf(-h2v, h2v, 1.0f);
                float uu = fmaf(aX[r], aX[r], fmaf(aY[r], aY[r], aW[r] * aW[r]));
                float lk = d2 * fmaf(-2.0f * h2v, uu, aT[r]);
                yr[r] = fmaf(h2v, w3.x, yr[r]);
                yi[r] = fmaf(h2v, w3.y, yi[r]);
                lr[r] = fmaf(lk, w3.x, lr[r]);
                li[r] = fmaf(lk, w3.y, li[r]);
            }
        }
        #pragma unroll
        for (int off = 1; off <= 8; off <<= 1) {
            #pragma unroll
            for (int r = 0; r < 4; ++r) {
                yr[r] += __shfl_xor(yr[r], off);
                yi[r] += __shfl_xor(yi[r], off);
                lr[r] += __shfl_xor(lr[r], off);
                li[r] += __shfl_xor(li[r], off);
            }
        }
        if (m == 0) {
            #pragma unroll
            for (int r = 0; r < 4; ++r) {
                float re = fmaf(4.0f, yr[r] + b30, lr[r]);
                float im = fmaf(4.0f, yi[r] + b31, li[r]);
                out[2 + p0 + qd * 4 + r] = re;
                lsum = fmaf(re, re, fmaf(im, im, lsum));
            }
        }
      } else {
        // ================= boundary tile: 16 points, forward only =================
        const int q0 = (t - TILES_INT) * 16;

        h8 FH[4];
        #pragma unroll
        for (int s = 0; s < 4; ++s) {
            const int j0 = s * 32 + qd * 8;
            h2 ph[4];
            #pragma unroll
            for (int i2 = 0; i2 < 4; ++i2) {
                const int jA = j0 + 2 * i2, jB = jA + 1;
                float4 PA = sP[jA], PB = sP[jB];
                float z1A = fmaf(x, PA.x, fmaf(y, PA.y, fmaf(z, PA.z, PA.w)));
                float z1B = fmaf(x, PB.x, fmaf(y, PB.y, fmaf(z, PB.z, PB.w)));
                ph[i2] = pk(ftanh(z1A), ftanh(z1B));
            }
            FH[s] = pack8(ph[0], ph[1], ph[2], ph[3]);
        }

        float yr[4] = {0,0,0,0}, yi[4] = {0,0,0,0};
        #pragma unroll
        for (int c = 0; c < 8; ++c) {
            f4 aZ = z4;
            #pragma unroll
            for (int s = 0; s < 4; ++s) {
                h8 bf = *(const h8*)&sB[(((s * 8 + c) * 64) + lane) * 8];
                aZ = __builtin_amdgcn_mfma_f32_16x16x32_f16(FH[s], bf, aZ, 0, 0, 0);
            }
            const int k = c * 16 + m;
            const float b2k = sB2[k];
            const float2 w3 = sW3[k];
            #pragma unroll
            for (int r = 0; r < 4; ++r) {
                float h2v = ftanh(aZ[r] + b2k);
                yr[r] = fmaf(h2v, w3.x, yr[r]);
                yi[r] = fmaf(h2v, w3.y, yi[r]);
            }
        }
        #pragma unroll
        for (int off = 1; off <= 8; off <<= 1) {
            #pragma unroll
            for (int r = 0; r < 4; ++r) {
                yr[r] += __shfl_xor(yr[r], off);
                yi[r] += __shfl_xor(yi[r], off);
            }
        }
        if (m == 0) {
            #pragma unroll
            for (int r = 0; r < 4; ++r) {
                float dr = yr[r] + b30 - gt[q0 + qd * 4 + r];
                float di = yi[r] + b31;
                bsum = fmaf(dr, dr, fmaf(di, di, bsum));
            }
        }
      }

      x = nx; y = ny; z = nz;
    }

    // wave-wide loss reduction, one atomic per wave
    #pragma unroll
    for (int off = 1; off < 64; off <<= 1) {
        lsum += __shfl_xor(lsum, off);
        bsum += __shfl_xor(bsum, off);
    }
    if (lane == 0) {
        atomicAdd(out,     lsum * (1.0f / (float)N_INT));
        atomicAdd(out + 1, bsum * (1.0f / (float)N_BC));
    }
}

extern "C" void kernel_launch(void* const* d_in, const int* in_sizes, int n_in,
                              void* d_out, int out_size, void* d_ws, size_t ws_size,
                              hipStream_t stream)
{
    const float* ci  = (const float*)d_in[0];   // coords_int (262144,3)
    const float* cb  = (const float*)d_in[1];   // coords_bc  (65536,3)
    const float* gt  = (const float*)d_in[2];   // gt_bc      (65536,1)
    const float* lat = (const float*)d_in[3];   // latent     (64,)
    const float* W1  = (const float*)d_in[4];   // (67,128)
    const float* b1  = (const float*)d_in[5];   // (128,)
    const float* W2  = (const float*)d_in[6];   // (128,128)
    const float* b2  = (const float*)d_in[7];   // (128,)
    const float* W3  = (const float*)d_in[8];   // (128,2)
    const float* b3  = (const float*)d_in[9];   // (2,)
    float* out = (float*)d_out;   // [loss_pde, loss_bc, re(helm)*N_INT]

    _Float16* wsB = (_Float16*)d_ws;                       // 32 KiB packed W2
    float*    wsF = (float*)((char*)d_ws + 32768);         // 4 KiB consts

    // zero the two loss accumulators (out is poisoned 0xAA before every call)
    hipMemsetAsync(d_out, 0, 2 * sizeof(float), stream);

    hipLaunchKernelGGL(pde_prep, dim3(1), dim3(256), 0, stream,
                       lat, W1, b1, W2, b2, W3, wsB, wsF);
    hipLaunchKernelGGL(pde_mfma, dim3(GRID), dim3(256), 0, stream,
                       ci, cb, gt, b3, wsB, wsF, out);
}

// Round 8
// 216.851 us; speedup vs baseline: 1.0537x; 1.0537x over previous
//
#include <hip/hip_runtime.h>

// ComplexSKPDELayer — MFMA formulation (R12 = R9 + GRID=768, pkrtz reverted).
// Ledger: R1 118us c-inner GRID=512. R6 636us spill ((512,4)). R7 150us
// c-inner GRID=1024 (+28% vs R1). R8 190us c-outer (256,3) spill. R9 128us
// c-outer (256,2) GRID=512: conflicts 0, prep offloaded, VGPR=128(+~20 acc).
// R11 164us c-outer GRID=1024 + pkrtz: VALU issue-time UNCHANGED (44us) ->
// pkrtz neutral (compiler already packs) and absmax 0.0078->0.0625 (RTZ);
// grid 512->1024 = +28% BOTH times tried (R7,R11): 1024 blocks at ~3/CU
// residency = 768 resident + 256-block second generation at 1/CU = fat tail
// (occupancy 18.3% = time-avg of 3/CU phase and tail phase).
// R12: GRID=768 = exactly 3 blocks/CU, one generation, no tail-gen.
// LDS 3x36.9=110.6<=160 OK; regs 3x~152 combined=456<=512 OK.
// Fork: occupancy ~24% -> dur ~100us. If occupancy stays ~16% -> 3rd block
// register-blocked -> pivot to 2-tile-per-wave ILP next round.
//
// Math (unchanged): per interior point, Helmholtz residual = 5 matvecs
// through W2: rows h1,g1x,g1y,g1z,s1 -> z2,ux,uy,uz,t; h2=tanh(z2+b2);
// lap_k=d2*(t-2*h2*(ux^2+uy^2+uz^2)); helm=(lap_k+4*h2)@W3(+4*b3).
// C/D layout col=lane&15(=k), row=(lane>>4)*4+reg(=point) -> lane-local
// epilogue + 16-lane shfl reduce. fp16 absmax ~0.008 vs 0.27 threshold.

#define N_INT 262144
#define N_BC  65536
#define HID   128
#define GRID  768
#define WPB   4                      // waves per 256-thread block
#define NWAVE (GRID * WPB)           // 3072 waves
#define TILES_INT (N_INT / 16)       // 16384
#define TILES_BC  (N_BC / 16)        // 4096
#define TILES_ALL (TILES_INT + TILES_BC)   // 20480 = 3072*6 + 2048 (grid-stride)

typedef _Float16 h8 __attribute__((ext_vector_type(8)));
typedef float    f4 __attribute__((ext_vector_type(4)));

__device__ __forceinline__ float ftanh(float x) {
    // tanh(x) = 1 - 2/(e^{2x}+1); v_exp_f32 + v_rcp_f32, ~2 ulp, inf-safe
    float e = __expf(2.0f * x);
    return 1.0f - 2.0f * __builtin_amdgcn_rcpf(e + 1.0f);
}

// ---------------- one-time prep: pack W2 + derived consts into ws ----------
// wsB (offset 0):      16384 fp16 = 32 KiB, B-frag order:
//   wsB[(((s*8+c)*64)+(qd*16+nn))*8+i] = fp16 W2[s*32+qd*8+i][c*16+nn]
// wsF (offset 32768):  1024 f32 = 4 KiB:
//   [0:512)   P[j] = float4{Wx,Wy,Wz,C1}[j], C1 = b1 + latent@W1[3:]
//   [512:640) Q2 = -2*(Wx^2+Wy^2+Wz^2)
//   [640:768) b2
//   [768:1024) W3 (128x2 interleaved)
extern "C" __global__ void pde_prep(const float* __restrict__ latent,
                                    const float* __restrict__ W1,
                                    const float* __restrict__ b1,
                                    const float* __restrict__ W2,
                                    const float* __restrict__ b2,
                                    const float* __restrict__ W3,
                                    _Float16* __restrict__ wsB,
                                    float* __restrict__ wsF)
{
    const int tid = threadIdx.x;
    for (int e = 0; e < 64; ++e) {
        int idx = e * 256 + tid;                   // coalesced over W2 row-major
        int j = idx >> 7, n = idx & 127;           // j = K row, n = out col
        int s = j >> 5, qd = (j >> 3) & 3, i = j & 7;
        int c = n >> 4,  nn = n & 15;
        wsB[(((s * 8 + c) * 64) + (qd * 16 + nn)) * 8 + i] = (_Float16)W2[idx];
    }
    // latent reduction: 2 threads per column, 32-deep chains, shfl combine
    {
        int col = tid >> 1, h = tid & 1;
        float acc = 0.0f;
        #pragma unroll
        for (int l = 0; l < 32; ++l)
            acc = fmaf(latent[32 * h + l], W1[(3 + 32 * h + l) * HID + col], acc);
        acc += __shfl_xor(acc, 1);
        if (h == 0) wsF[4 * col + 3] = acc + b1[col];   // P[col].w = C1
    }
    if (tid < HID) {
        float wx = W1[tid], wy = W1[HID + tid], wz = W1[2 * HID + tid];
        wsF[4 * tid]     = wx;                          // P[tid].x
        wsF[4 * tid + 1] = wy;                          // P[tid].y
        wsF[4 * tid + 2] = wz;                          // P[tid].z
        wsF[512 + tid] = -2.0f * fmaf(wx, wx, fmaf(wy, wy, wz * wz));
        wsF[640 + tid] = b2[tid];
        wsF[768 + 2 * tid]     = W3[2 * tid];
        wsF[768 + 2 * tid + 1] = W3[2 * tid + 1];
    }
}

extern "C" __global__ __launch_bounds__(256, 2)
void pde_mfma(const float* __restrict__ ci, const float* __restrict__ cb,
              const float* __restrict__ gt, const float* __restrict__ b3,
              const _Float16* __restrict__ wsB, const float* __restrict__ wsF,
              float* __restrict__ out)
{
    __shared__ float4 sBv[2048];       // 32 KiB packed W2 B-frags
    __shared__ float4 sFv[256];        // 4 KiB derived consts
    _Float16* sB = (_Float16*)sBv;
    const float*  sF  = (const float*)sFv;
    const float4* sP  = (const float4*)sF;          // {wx,wy,wz,c1}[j]
    const float*  sQ2 = sF + 512;
    const float*  sB2 = sF + 640;
    const float2* sW3 = (const float2*)(sF + 768);

    const int tid = threadIdx.x;

    // conflict-free staging copy: 32 KiB + 4 KiB as float4
    #pragma unroll
    for (int e = 0; e < 8; ++e)
        sBv[e * 256 + tid] = ((const float4*)wsB)[e * 256 + tid];
    sFv[tid] = ((const float4*)wsF)[tid];
    __syncthreads();

    const int lane = tid & 63;
    const int m    = lane & 15;        // point-in-tile
    const int qd   = lane >> 4;        // quad: k-subrange / C row block
    const int wgid = blockIdx.x * WPB + (tid >> 6);
    const float b30 = b3[0], b31 = b3[1];
    const f4 z4 = {0.0f, 0.0f, 0.0f, 0.0f};

    float lsum = 0.0f, bsum = 0.0f;

    // coordinate pipeline: coords for tile t preloaded before body
    int t = wgid;
    const float* cp0 = (t < TILES_INT) ? (ci + 3 * (t * 16 + m))
                                       : (cb + 3 * ((t - TILES_INT) * 16 + m));
    float x = cp0[0], y = cp0[1], z = cp0[2];

    for (; t < TILES_ALL; t += NWAVE) {
      // issue next tile's coord loads now; consumed next iteration
      float nx, ny, nz;
      {
        int tn = t + NWAVE;
        if (tn < TILES_ALL) {
            const float* np = (tn < TILES_INT) ? (ci + 3 * (tn * 16 + m))
                                               : (cb + 3 * ((tn - TILES_INT) * 16 + m));
            nx = np[0]; ny = np[1]; nz = np[2];
        } else { nx = ny = nz = 0.0f; }
      }

      if (t < TILES_INT) {
        // ================= interior tile: 16 points =================
        const int p0 = t * 16;

        // A-frags for all 4 k-slices (80 VGPRs live)
        h8 FH[4], FX[4], FY[4], FZ[4], FT[4];
        #pragma unroll
        for (int s = 0; s < 4; ++s) {
            const int j0 = s * 32 + qd * 8;
            #pragma unroll
            for (int i = 0; i < 8; ++i) {
                const int j = j0 + i;
                float4 P = sP[j];                  // {wx,wy,wz,c1}
                float z1 = fmaf(x, P.x, fmaf(y, P.y, fmaf(z, P.z, P.w)));
                float h  = ftanh(z1);
                float d  = fmaf(-h, h, 1.0f);
                FH[s][i] = (_Float16)h;
                FX[s][i] = (_Float16)(d * P.x);
                FY[s][i] = (_Float16)(d * P.y);
                FZ[s][i] = (_Float16)(d * P.z);
                FT[s][i] = (_Float16)(sQ2[j] * h * d);
            }
        }

        float yr[4] = {0,0,0,0}, yi[4] = {0,0,0,0};
        float lr[4] = {0,0,0,0}, li[4] = {0,0,0,0};
        #pragma unroll
        for (int c = 0; c < 8; ++c) {
            f4 aZ = z4, aX = z4, aY = z4, aW = z4, aT = z4;
            #pragma unroll
            for (int s = 0; s < 4; ++s) {
                h8 bf = *(const h8*)&sB[(((s * 8 + c) * 64) + lane) * 8];
                aZ = __builtin_amdgcn_mfma_f32_16x16x32_f16(FH[s], bf, aZ, 0, 0, 0);
                aX = __builtin_amdgcn_mfma_f32_16x16x32_f16(FX[s], bf, aX, 0, 0, 0);
                aY = __builtin_amdgcn_mfma_f32_16x16x32_f16(FY[s], bf, aY, 0, 0, 0);
                aW = __builtin_amdgcn_mfma_f32_16x16x32_f16(FZ[s], bf, aW, 0, 0, 0);
                aT = __builtin_amdgcn_mfma_f32_16x16x32_f16(FT[s], bf, aT, 0, 0, 0);
            }
            // fused epilogue for this c: lane-local (point=qd*4+r, k=c*16+m)
            const int k = c * 16 + m;
            const float b2k = sB2[k];
            const float2 w3 = sW3[k];
            #pragma unroll
            for (int r = 0; r < 4; ++r) {
                float h2v = ftanh(aZ[r] + b2k);
                float d2 = fmaf(-h2v, h2v, 1.0f);
                float uu = fmaf(aX[r], aX[r], fmaf(aY[r], aY[r], aW[r] * aW[r]));
                float lk = d2 * fmaf(-2.0f * h2v, uu, aT[r]);
                yr[r] = fmaf(h2v, w3.x, yr[r]);
                yi[r] = fmaf(h2v, w3.y, yi[r]);
                lr[r] = fmaf(lk, w3.x, lr[r]);
                li[r] = fmaf(lk, w3.y, li[r]);
            }
        }
        #pragma unroll
        for (int off = 1; off <= 8; off <<= 1) {
            #pragma unroll
            for (int r = 0; r < 4; ++r) {
                yr[r] += __shfl_xor(yr[r], off);
                yi[r] += __shfl_xor(yi[r], off);
                lr[r] += __shfl_xor(lr[r], off);
                li[r] += __shfl_xor(li[r], off);
            }
        }
        if (m == 0) {
            #pragma unroll
            for (int r = 0; r < 4; ++r) {
                float re = fmaf(4.0f, yr[r] + b30, lr[r]);
                float im = fmaf(4.0f, yi[r] + b31, li[r]);
                out[2 + p0 + qd * 4 + r] = re;
                lsum = fmaf(re, re, fmaf(im, im, lsum));
            }
        }
      } else {
        // ================= boundary tile: 16 points, forward only =================
        const int q0 = (t - TILES_INT) * 16;

        h8 FH[4];
        #pragma unroll
        for (int s = 0; s < 4; ++s) {
            const int j0 = s * 32 + qd * 8;
            #pragma unroll
            for (int i = 0; i < 8; ++i) {
                const int j = j0 + i;
                float4 P = sP[j];
                float z1 = fmaf(x, P.x, fmaf(y, P.y, fmaf(z, P.z, P.w)));
                FH[s][i] = (_Float16)ftanh(z1);
            }
        }

        float yr[4] = {0,0,0,0}, yi[4] = {0,0,0,0};
        #pragma unroll
        for (int c = 0; c < 8; ++c) {
            f4 aZ = z4;
            #pragma unroll
            for (int s = 0; s < 4; ++s) {
                h8 bf = *(const h8*)&sB[(((s * 8 + c) * 64) + lane) * 8];
                aZ = __builtin_amdgcn_mfma_f32_16x16x32_f16(FH[s], bf, aZ, 0, 0, 0);
            }
            const int k = c * 16 + m;
            const float b2k = sB2[k];
            const float2 w3 = sW3[k];
            #pragma unroll
            for (int r = 0; r < 4; ++r) {
                float h2v = ftanh(aZ[r] + b2k);
                yr[r] = fmaf(h2v, w3.x, yr[r]);
                yi[r] = fmaf(h2v, w3.y, yi[r]);
            }
        }
        #pragma unroll
        for (int off = 1; off <= 8; off <<= 1) {
            #pragma unroll
            for (int r = 0; r < 4; ++r) {
                yr[r] += __shfl_xor(yr[r], off);
                yi[r] += __shfl_xor(yi[r], off);
            }
        }
        if (m == 0) {
            #pragma unroll
            for (int r = 0; r < 4; ++r) {
                float dr = yr[r] + b30 - gt[q0 + qd * 4 + r];
                float di = yi[r] + b31;
                bsum = fmaf(dr, dr, fmaf(di, di, bsum));
            }
        }
      }

      x = nx; y = ny; z = nz;
    }

    // wave-wide loss reduction, one atomic per wave
    #pragma unroll
    for (int off = 1; off < 64; off <<= 1) {
        lsum += __shfl_xor(lsum, off);
        bsum += __shfl_xor(bsum, off);
    }
    if (lane == 0) {
        atomicAdd(out,     lsum * (1.0f / (float)N_INT));
        atomicAdd(out + 1, bsum * (1.0f / (float)N_BC));
    }
}

extern "C" void kernel_launch(void* const* d_in, const int* in_sizes, int n_in,
                              void* d_out, int out_size, void* d_ws, size_t ws_size,
                              hipStream_t stream)
{
    const float* ci  = (const float*)d_in[0];   // coords_int (262144,3)
    const float* cb  = (const float*)d_in[1];   // coords_bc  (65536,3)
    const float* gt  = (const float*)d_in[2];   // gt_bc      (65536,1)
    const float* lat = (const float*)d_in[3];   // latent     (64,)
    const float* W1  = (const float*)d_in[4];   // (67,128)
    const float* b1  = (const float*)d_in[5];   // (128,)
    const float* W2  = (const float*)d_in[6];   // (128,128)
    const float* b2  = (const float*)d_in[7];   // (128,)
    const float* W3  = (const float*)d_in[8];   // (128,2)
    const float* b3  = (const float*)d_in[9];   // (2,)
    float* out = (float*)d_out;   // [loss_pde, loss_bc, re(helm)*N_INT]

    _Float16* wsB = (_Float16*)d_ws;                       // 32 KiB packed W2
    float*    wsF = (float*)((char*)d_ws + 32768);         // 4 KiB consts

    // zero the two loss accumulators (out is poisoned 0xAA before every call)
    hipMemsetAsync(d_out, 0, 2 * sizeof(float), stream);

    hipLaunchKernelGGL(pde_prep, dim3(1), dim3(256), 0, stream,
                       lat, W1, b1, W2, b2, W3, wsB, wsF);
    hipLaunchKernelGGL(pde_mfma, dim3(GRID), dim3(256), 0, stream,
                       ci, cb, gt, b3, wsB, wsF, out);
}

// Round 9
// 198.934 us; speedup vs baseline: 1.1486x; 1.0901x over previous
//
#include <hip/hip_runtime.h>

// ComplexSKPDELayer — MFMA formulation (R13 = R1 c-inner + prep offload).
// Ledger: R1 118us c-inner GRID=512 (256,2), VGPR=128+64agpr, incl ~16us/blk
// inline prep -> compute ~102us. R6 636us spill ((512,4)). R7/R11/R12: grid
// >512 regressed in ALL structures (tail generations; residency hard-capped
// at 2 blocks/CU — agpr padded to 64 -> ~192 combined regs -> 2 waves/SIMD).
// R8 190us: (256,3) spills c-outer. R9 128us: c-outer serializes
// {MFMA(c)->epilogue(c)}x8 per tile -> 25% slower than c-inner despite prep
// offload. R13: c-inner MFMA stream (all 160 MFMA, frag-gen(s+1) overlaps
// MFMA(s), single high-ILP epilogue) + R9's prep kernel (conflicts 0, no
// per-block prep) + float4 sP + coord prefetch. GRID=512, (256,2).
//
// Math: per interior point, Helmholtz residual = 5 matvecs through W2:
// rows h1,g1x,g1y,g1z,s1 -> z2,ux,uy,uz,t; h2=tanh(z2+b2);
// lap_k=d2*(t-2*h2*(ux^2+uy^2+uz^2)); helm=(lap_k+4*h2)@W3(+4*b3).
// C/D layout col=lane&15(=k), row=(lane>>4)*4+reg(=point) -> lane-local
// epilogue + 16-lane shfl reduce. fp16 absmax ~0.008 vs 0.27 threshold.

#define N_INT 262144
#define N_BC  65536
#define HID   128
#define GRID  512
#define WPB   4                      // waves per 256-thread block
#define NWAVE (GRID * WPB)           // 2048 waves
#define TILES_INT (N_INT / 16)       // 16384
#define TILES_BC  (N_BC / 16)        // 4096
#define TILES_ALL (TILES_INT + TILES_BC)   // 20480 = 2048 * 10, no tail

typedef _Float16 h8 __attribute__((ext_vector_type(8)));
typedef float    f4 __attribute__((ext_vector_type(4)));

__device__ __forceinline__ float ftanh(float x) {
    // tanh(x) = 1 - 2/(e^{2x}+1); v_exp_f32 + v_rcp_f32, ~2 ulp, inf-safe
    float e = __expf(2.0f * x);
    return 1.0f - 2.0f * __builtin_amdgcn_rcpf(e + 1.0f);
}

// ---------------- one-time prep: pack W2 + derived consts into ws ----------
// wsB (offset 0):      16384 fp16 = 32 KiB, B-frag order:
//   wsB[(((s*8+c)*64)+(qd*16+nn))*8+i] = fp16 W2[s*32+qd*8+i][c*16+nn]
// wsF (offset 32768):  1024 f32 = 4 KiB:
//   [0:512)   P[j] = float4{Wx,Wy,Wz,C1}[j], C1 = b1 + latent@W1[3:]
//   [512:640) Q2 = -2*(Wx^2+Wy^2+Wz^2)
//   [640:768) b2
//   [768:1024) W3 (128x2 interleaved)
extern "C" __global__ void pde_prep(const float* __restrict__ latent,
                                    const float* __restrict__ W1,
                                    const float* __restrict__ b1,
                                    const float* __restrict__ W2,
                                    const float* __restrict__ b2,
                                    const float* __restrict__ W3,
                                    _Float16* __restrict__ wsB,
                                    float* __restrict__ wsF)
{
    const int tid = threadIdx.x;
    for (int e = 0; e < 64; ++e) {
        int idx = e * 256 + tid;                   // coalesced over W2 row-major
        int j = idx >> 7, n = idx & 127;           // j = K row, n = out col
        int s = j >> 5, qd = (j >> 3) & 3, i = j & 7;
        int c = n >> 4,  nn = n & 15;
        wsB[(((s * 8 + c) * 64) + (qd * 16 + nn)) * 8 + i] = (_Float16)W2[idx];
    }
    // latent reduction: 2 threads per column, 32-deep chains, shfl combine
    {
        int col = tid >> 1, h = tid & 1;
        float acc = 0.0f;
        #pragma unroll
        for (int l = 0; l < 32; ++l)
            acc = fmaf(latent[32 * h + l], W1[(3 + 32 * h + l) * HID + col], acc);
        acc += __shfl_xor(acc, 1);
        if (h == 0) wsF[4 * col + 3] = acc + b1[col];   // P[col].w = C1
    }
    if (tid < HID) {
        float wx = W1[tid], wy = W1[HID + tid], wz = W1[2 * HID + tid];
        wsF[4 * tid]     = wx;                          // P[tid].x
        wsF[4 * tid + 1] = wy;                          // P[tid].y
        wsF[4 * tid + 2] = wz;                          // P[tid].z
        wsF[512 + tid] = -2.0f * fmaf(wx, wx, fmaf(wy, wy, wz * wz));
        wsF[640 + tid] = b2[tid];
        wsF[768 + 2 * tid]     = W3[2 * tid];
        wsF[768 + 2 * tid + 1] = W3[2 * tid + 1];
    }
}

extern "C" __global__ __launch_bounds__(256, 2)
void pde_mfma(const float* __restrict__ ci, const float* __restrict__ cb,
              const float* __restrict__ gt, const float* __restrict__ b3,
              const _Float16* __restrict__ wsB, const float* __restrict__ wsF,
              float* __restrict__ out)
{
    __shared__ float4 sBv[2048];       // 32 KiB packed W2 B-frags
    __shared__ float4 sFv[256];        // 4 KiB derived consts
    _Float16* sB = (_Float16*)sBv;
    const float*  sF  = (const float*)sFv;
    const float4* sP  = (const float4*)sF;          // {wx,wy,wz,c1}[j]
    const float*  sQ2 = sF + 512;
    const float*  sB2 = sF + 640;
    const float2* sW3 = (const float2*)(sF + 768);

    const int tid = threadIdx.x;

    // conflict-free staging copy: 32 KiB + 4 KiB as float4
    #pragma unroll
    for (int e = 0; e < 8; ++e)
        sBv[e * 256 + tid] = ((const float4*)wsB)[e * 256 + tid];
    sFv[tid] = ((const float4*)wsF)[tid];
    __syncthreads();

    const int lane = tid & 63;
    const int m    = lane & 15;        // point-in-tile
    const int qd   = lane >> 4;        // quad: k-subrange / C row block
    const int wgid = blockIdx.x * WPB + (tid >> 6);
    const float b30 = b3[0], b31 = b3[1];
    const f4 z4 = {0.0f, 0.0f, 0.0f, 0.0f};

    float lsum = 0.0f, bsum = 0.0f;

    // coordinate pipeline: coords for tile t preloaded before body
    int t = wgid;
    const float* cp0 = (t < TILES_INT) ? (ci + 3 * (t * 16 + m))
                                       : (cb + 3 * ((t - TILES_INT) * 16 + m));
    float x = cp0[0], y = cp0[1], z = cp0[2];

    for (; t < TILES_ALL; t += NWAVE) {
      // issue next tile's coord loads now; consumed next iteration
      float nx, ny, nz;
      {
        int tn = t + NWAVE;
        if (tn < TILES_ALL) {
            const float* np = (tn < TILES_INT) ? (ci + 3 * (tn * 16 + m))
                                               : (cb + 3 * ((tn - TILES_INT) * 16 + m));
            nx = np[0]; ny = np[1]; nz = np[2];
        } else { nx = ny = nz = 0.0f; }
      }

      if (t < TILES_INT) {
        // ================= interior tile: 16 points =================
        const int p0 = t * 16;

        f4 aZ[8], aX[8], aY[8], aW[8], aT[8];
        #pragma unroll
        for (int c = 0; c < 8; ++c) { aZ[c]=z4; aX[c]=z4; aY[c]=z4; aW[c]=z4; aT[c]=z4; }

        #pragma unroll
        for (int s = 0; s < 4; ++s) {
            const int j0 = s * 32 + qd * 8;
            h8 fh, fx, fy, fz, ft;
            #pragma unroll
            for (int i = 0; i < 8; ++i) {
                const int j = j0 + i;
                float4 P = sP[j];                  // {wx,wy,wz,c1}
                float z1 = fmaf(x, P.x, fmaf(y, P.y, fmaf(z, P.z, P.w)));
                float h  = ftanh(z1);
                float d  = fmaf(-h, h, 1.0f);
                fh[i] = (_Float16)h;
                fx[i] = (_Float16)(d * P.x);
                fy[i] = (_Float16)(d * P.y);
                fz[i] = (_Float16)(d * P.z);
                ft[i] = (_Float16)(sQ2[j] * h * d);
            }
            #pragma unroll
            for (int c = 0; c < 8; ++c) {
                h8 bf = *(const h8*)&sB[(((s * 8 + c) * 64) + lane) * 8];
                aZ[c] = __builtin_amdgcn_mfma_f32_16x16x32_f16(fh, bf, aZ[c], 0, 0, 0);
                aX[c] = __builtin_amdgcn_mfma_f32_16x16x32_f16(fx, bf, aX[c], 0, 0, 0);
                aY[c] = __builtin_amdgcn_mfma_f32_16x16x32_f16(fy, bf, aY[c], 0, 0, 0);
                aW[c] = __builtin_amdgcn_mfma_f32_16x16x32_f16(fz, bf, aW[c], 0, 0, 0);
                aT[c] = __builtin_amdgcn_mfma_f32_16x16x32_f16(ft, bf, aT[c], 0, 0, 0);
            }
        }

        // epilogue: lane-local per (point=qd*4+r, k=c*16+m)
        float yr[4] = {0,0,0,0}, yi[4] = {0,0,0,0};
        float lr[4] = {0,0,0,0}, li[4] = {0,0,0,0};
        #pragma unroll
        for (int c = 0; c < 8; ++c) {
            const int k = c * 16 + m;
            const float b2k = sB2[k];
            const float2 w3 = sW3[k];
            #pragma unroll
            for (int r = 0; r < 4; ++r) {
                float h2 = ftanh(aZ[c][r] + b2k);
                float d2 = fmaf(-h2, h2, 1.0f);
                float uu = fmaf(aX[c][r], aX[c][r],
                            fmaf(aY[c][r], aY[c][r], aW[c][r] * aW[c][r]));
                float lk = d2 * fmaf(-2.0f * h2, uu, aT[c][r]);
                yr[r] = fmaf(h2, w3.x, yr[r]);
                yi[r] = fmaf(h2, w3.y, yi[r]);
                lr[r] = fmaf(lk, w3.x, lr[r]);
                li[r] = fmaf(lk, w3.y, li[r]);
            }
        }
        #pragma unroll
        for (int off = 1; off <= 8; off <<= 1) {
            #pragma unroll
            for (int r = 0; r < 4; ++r) {
                yr[r] += __shfl_xor(yr[r], off);
                yi[r] += __shfl_xor(yi[r], off);
                lr[r] += __shfl_xor(lr[r], off);
                li[r] += __shfl_xor(li[r], off);
            }
        }
        if (m == 0) {
            #pragma unroll
            for (int r = 0; r < 4; ++r) {
                float re = fmaf(4.0f, yr[r] + b30, lr[r]);
                float im = fmaf(4.0f, yi[r] + b31, li[r]);
                out[2 + p0 + qd * 4 + r] = re;
                lsum = fmaf(re, re, fmaf(im, im, lsum));
            }
        }
      } else {
        // ================= boundary tile: 16 points, forward only =================
        const int q0 = (t - TILES_INT) * 16;

        f4 bZ[8];
        #pragma unroll
        for (int c = 0; c < 8; ++c) bZ[c] = z4;

        #pragma unroll
        for (int s = 0; s < 4; ++s) {
            const int j0 = s * 32 + qd * 8;
            h8 fh;
            #pragma unroll
            for (int i = 0; i < 8; ++i) {
                const int j = j0 + i;
                float4 P = sP[j];
                float z1 = fmaf(x, P.x, fmaf(y, P.y, fmaf(z, P.z, P.w)));
                fh[i] = (_Float16)ftanh(z1);
            }
            #pragma unroll
            for (int c = 0; c < 8; ++c) {
                h8 bf = *(const h8*)&sB[(((s * 8 + c) * 64) + lane) * 8];
                bZ[c] = __builtin_amdgcn_mfma_f32_16x16x32_f16(fh, bf, bZ[c], 0, 0, 0);
            }
        }

        float yr[4] = {0,0,0,0}, yi[4] = {0,0,0,0};
        #pragma unroll
        for (int c = 0; c < 8; ++c) {
            const int k = c * 16 + m;
            const float b2k = sB2[k];
            const float2 w3 = sW3[k];
            #pragma unroll
            for (int r = 0; r < 4; ++r) {
                float h2 = ftanh(bZ[c][r] + b2k);
                yr[r] = fmaf(h2, w3.x, yr[r]);
                yi[r] = fmaf(h2, w3.y, yi[r]);
            }
        }
        #pragma unroll
        for (int off = 1; off <= 8; off <<= 1) {
            #pragma unroll
            for (int r = 0; r < 4; ++r) {
                yr[r] += __shfl_xor(yr[r], off);
                yi[r] += __shfl_xor(yi[r], off);
            }
        }
        if (m == 0) {
            #pragma unroll
            for (int r = 0; r < 4; ++r) {
                float dr = yr[r] + b30 - gt[q0 + qd * 4 + r];
                float di = yi[r] + b31;
                bsum = fmaf(dr, dr, fmaf(di, di, bsum));
            }
        }
      }

      x = nx; y = ny; z = nz;
    }

    // wave-wide loss reduction, one atomic per wave
    #pragma unroll
    for (int off = 1; off < 64; off <<= 1) {
        lsum += __shfl_xor(lsum, off);
        bsum += __shfl_xor(bsum, off);
    }
    if (lane == 0) {
        atomicAdd(out,     lsum * (1.0f / (float)N_INT));
        atomicAdd(out + 1, bsum * (1.0f / (float)N_BC));
    }
}

extern "C" void kernel_launch(void* const* d_in, const int* in_sizes, int n_in,
                              void* d_out, int out_size, void* d_ws, size_t ws_size,
                              hipStream_t stream)
{
    const float* ci  = (const float*)d_in[0];   // coords_int (262144,3)
    const float* cb  = (const float*)d_in[1];   // coords_bc  (65536,3)
    const float* gt  = (const float*)d_in[2];   // gt_bc      (65536,1)
    const float* lat = (const float*)d_in[3];   // latent     (64,)
    const float* W1  = (const float*)d_in[4];   // (67,128)
    const float* b1  = (const float*)d_in[5];   // (128,)
    const float* W2  = (const float*)d_in[6];   // (128,128)
    const float* b2  = (const float*)d_in[7];   // (128,)
    const float* W3  = (const float*)d_in[8];   // (128,2)
    const float* b3  = (const float*)d_in[9];   // (2,)
    float* out = (float*)d_out;   // [loss_pde, loss_bc, re(helm)*N_INT]

    _Float16* wsB = (_Float16*)d_ws;                       // 32 KiB packed W2
    float*    wsF = (float*)((char*)d_ws + 32768);         // 4 KiB consts

    // zero the two loss accumulators (out is poisoned 0xAA before every call)
    hipMemsetAsync(d_out, 0, 2 * sizeof(float), stream);

    hipLaunchKernelGGL(pde_prep, dim3(1), dim3(256), 0, stream,
                       lat, W1, b1, W2, b2, W3, wsB, wsF);
    hipLaunchKernelGGL(pde_mfma, dim3(GRID), dim3(256), 0, stream,
                       ci, cb, gt, b3, wsB, wsF, out);
}